// Round 1
// baseline (533.238 us; speedup 1.0000x reference)
//
#include <hip/hip_runtime.h>
#include <hip/hip_bf16.h>

// JointNet: out[b,t,u,v] = sum_j tanh(e[b,t,j] + d[b,u,j]) * W_out[v,j] + b_out[v]
//   e = h_enc @ W_enc^T + b_enc   (1600 x 512)
//   d = h_dec @ W_dec^T           (400 x 512)
// Main GEMM: M=80000, N=1024, K=512 (bf16 MFMA, m97-style 128x128 tile).

typedef short bf16x8 __attribute__((ext_vector_type(8)));
typedef float fx4 __attribute__((ext_vector_type(4)));

static constexpr int KD = 512;   // J = D_enc = D_dec = K
static constexpr int V = 1024;
static constexpr int M_BIG = 80000;  // B*T*U

__device__ inline unsigned short f2bf(float f) {
    union { float f; unsigned u; } v; v.f = f;
    unsigned r = v.u + 0x7fffu + ((v.u >> 16) & 1u);
    return (unsigned short)(r >> 16);
}
__device__ inline float bf2f(unsigned short h) {
    union { float f; unsigned u; } v; v.u = ((unsigned)h) << 16; return v.f;
}
__device__ inline float fast_tanh(float x) {
    // tanh(x) = 1 - 2/(e^{2x}+1);  e^{2x} = 2^{x * 2*log2(e)}
    float p = __builtin_amdgcn_exp2f(x * 2.885390081777926f);
    return 1.0f - 2.0f * __builtin_amdgcn_rcpf(p + 1.0f);
}
__device__ inline void gld_lds16(const void* g, void* l) {
    __builtin_amdgcn_global_load_lds(
        (const __attribute__((address_space(1))) void*)g,
        (__attribute__((address_space(3))) void*)l, 16, 0, 0);
}

// ---------------- small GEMM: out[m,n] = sum_k A[m,k]*W[n,k] (+bias[n]) ----
// 3-phase bf16 split (hiA*hiW + loA*hiW + hiA*loW) for near-fp32 accuracy.
// Tile 64x64, BK=32, 256 threads = 4 waves (2x2), wave tile 32x32.
__global__ __launch_bounds__(256) void gemm_ed(
    const float* __restrict__ A, const float* __restrict__ W,
    const float* __restrict__ bias, float* __restrict__ out, int Mrows) {
    __shared__ unsigned short As[64 * 32];
    __shared__ unsigned short Ws[64 * 32];
    const int t = threadIdx.x;
    const int lane = t & 63, wid = t >> 6;
    const int m0 = blockIdx.x * 64, n0 = blockIdx.y * 64;
    const int wm = (wid & 1) * 32, wn = (wid >> 1) * 32;

    fx4 acc[2][2];
    const fx4 z4 = {0.f, 0.f, 0.f, 0.f};
    acc[0][0] = z4; acc[0][1] = z4; acc[1][0] = z4; acc[1][1] = z4;

    const int sr = t >> 2;             // staged row 0..63
    const int skc = (t & 3) * 8;       // k chunk start
    const int ar = (m0 + sr < Mrows) ? (m0 + sr) : (Mrows - 1);
    const float* Ap = A + (size_t)ar * KD + skc;
    const float* Wp = W + (size_t)(n0 + sr) * KD + skc;
    unsigned short* asl = &As[sr * 32 + skc];
    unsigned short* wsl = &Ws[sr * 32 + skc];

    for (int ph = 0; ph < 3; ph++) {
        const int amode = (ph == 1);  // take lo(A) on phase 1
        const int wmode = (ph == 2);  // take lo(W) on phase 2
        for (int kb = 0; kb < 16; kb++) {
            const int k0 = kb * 32;
            fx4 a0 = *(const fx4*)(Ap + k0);
            fx4 a1 = *(const fx4*)(Ap + k0 + 4);
            fx4 w0 = *(const fx4*)(Wp + k0);
            fx4 w1 = *(const fx4*)(Wp + k0 + 4);
            unsigned short pa[8], pw[8];
            #pragma unroll
            for (int i = 0; i < 4; i++) {
                float av0 = a0[i], av1 = a1[i], wv0 = w0[i], wv1 = w1[i];
                unsigned short h;
                h = f2bf(av0); pa[i]     = amode ? f2bf(av0 - bf2f(h)) : h;
                h = f2bf(av1); pa[i + 4] = amode ? f2bf(av1 - bf2f(h)) : h;
                h = f2bf(wv0); pw[i]     = wmode ? f2bf(wv0 - bf2f(h)) : h;
                h = f2bf(wv1); pw[i + 4] = wmode ? f2bf(wv1 - bf2f(h)) : h;
            }
            *(bf16x8*)asl = *(bf16x8*)pa;
            *(bf16x8*)wsl = *(bf16x8*)pw;
            __syncthreads();
            bf16x8 af[2], wf[2];
            #pragma unroll
            for (int f = 0; f < 2; f++) {
                af[f] = *(const bf16x8*)&As[(wm + f * 16 + (lane & 15)) * 32 + (lane >> 4) * 8];
                wf[f] = *(const bf16x8*)&Ws[(wn + f * 16 + (lane & 15)) * 32 + (lane >> 4) * 8];
            }
            #pragma unroll
            for (int fm = 0; fm < 2; fm++)
                #pragma unroll
                for (int fn = 0; fn < 2; fn++)
                    acc[fm][fn] = __builtin_amdgcn_mfma_f32_16x16x32_bf16(
                        af[fm], wf[fn], acc[fm][fn], 0, 0, 0);
            __syncthreads();
        }
    }
    // epilogue: C/D layout col=lane&15, row=(lane>>4)*4+reg
    const int colb = n0 + wn + (lane & 15);
    const int rowb = m0 + wm + (lane >> 4) * 4;
    float bo[2];
    bo[0] = bias ? bias[colb] : 0.f;
    bo[1] = bias ? bias[colb + 16] : 0.f;
    #pragma unroll
    for (int fm = 0; fm < 2; fm++) {
        #pragma unroll
        for (int r = 0; r < 4; r++) {
            int row = rowb + fm * 16 + r;
            if (row < Mrows) {
                float* op = out + (size_t)row * KD;
                op[colb] = acc[fm][0][r] + bo[0];
                op[colb + 16] = acc[fm][1][r] + bo[1];
            }
        }
    }
}

// ---------------- fp32 -> bf16 convert (W_out) -----------------------------
__global__ __launch_bounds__(256) void cvt_bf16(
    const float* __restrict__ in, unsigned short* __restrict__ o, int n) {
    int i = (blockIdx.x * 256 + threadIdx.x) * 8;
    if (i >= n) return;
    fx4 a = *(const fx4*)(in + i);
    fx4 b = *(const fx4*)(in + i + 4);
    unsigned short p[8];
    #pragma unroll
    for (int j = 0; j < 4; j++) { p[j] = f2bf(a[j]); p[j + 4] = f2bf(b[j]); }
    *(bf16x8*)(o + i) = *(bf16x8*)p;
}

// ---------------- Z = tanh(e + d) materialized in bf16 ---------------------
// m = (b*T + t)*U + u ; bt = m/50 ; b = m/10000 ; d row = b*50 + u
__global__ __launch_bounds__(256) void tanh_z(
    const float* __restrict__ e, const float* __restrict__ d,
    unsigned short* __restrict__ Z) {
    const int t = threadIdx.x;
    const int m = blockIdx.x * 4 + (t >> 6);
    const int kc = (t & 63) * 8;
    const int bt = m / 50;
    const int u = m - bt * 50;
    const int b = m / 10000;
    const float* ep = e + (size_t)bt * KD + kc;
    const float* dp = d + (size_t)(b * 50 + u) * KD + kc;
    fx4 e0 = *(const fx4*)ep, e1 = *(const fx4*)(ep + 4);
    fx4 d0 = *(const fx4*)dp, d1 = *(const fx4*)(dp + 4);
    unsigned short p[8];
    #pragma unroll
    for (int i = 0; i < 4; i++) {
        p[i] = f2bf(fast_tanh(e0[i] + d0[i]));
        p[i + 4] = f2bf(fast_tanh(e1[i] + d1[i]));
    }
    *(bf16x8*)(Z + (size_t)m * KD + kc) = *(bf16x8*)p;
}

// ---------------- main GEMM: out = Z @ W_out^T + b_out ---------------------
// M=80000 (625 tiles), N=1024 (8 tiles), K=512 (16 x BK32).
// 128x128 tile, 256 threads = 4 waves (2x2), wave tile 64x64 (4x4 frags).
// A and B staged via global_load_lds width=16 (m97 structure).
__global__ __launch_bounds__(256) void gemm_out_k(
    const unsigned short* __restrict__ Z, const unsigned short* __restrict__ Wb,
    const float* __restrict__ b_out, float* __restrict__ out) {
    __shared__ unsigned short As[128 * 32];
    __shared__ unsigned short Bs[128 * 32];
    const int t = threadIdx.x;
    const int lane = t & 63, wid = t >> 6;
    const int bid = blockIdx.x;
    const int n0 = (bid & 7) * 128;    // XCD-pinned N tile (bid%8 -> XCD)
    const int m0 = (bid >> 3) * 128;
    const int wm = (wid & 1) * 64, wn = (wid >> 1) * 64;

    fx4 acc[4][4];
    const fx4 z4 = {0.f, 0.f, 0.f, 0.f};
    #pragma unroll
    for (int i = 0; i < 4; i++)
        #pragma unroll
        for (int j = 0; j < 4; j++) acc[i][j] = z4;

    // staging: chunk c = (wid*2+q)*64 + lane covers row c>>2, k-part (c&3)*8
    size_t gA[2], gB[2];
    unsigned short* lA[2];
    unsigned short* lB[2];
    #pragma unroll
    for (int q = 0; q < 2; q++) {
        int c = (wid * 2 + q) * 64 + lane;
        int r = c >> 2, kc = (c & 3) * 8;
        gA[q] = (size_t)(m0 + r) * KD + kc;
        gB[q] = (size_t)(n0 + r) * KD + kc;
        lA[q] = &As[(wid * 2 + q) * 512];   // wave-uniform base; HW adds lane*16
        lB[q] = &Bs[(wid * 2 + q) * 512];
    }

    for (int kb = 0; kb < 16; kb++) {
        const int k0 = kb * 32;
        #pragma unroll
        for (int q = 0; q < 2; q++) {
            gld_lds16(Z + gA[q] + k0, lA[q]);
            gld_lds16(Wb + gB[q] + k0, lB[q]);
        }
        __syncthreads();
        bf16x8 af[4], bf[4];
        #pragma unroll
        for (int f = 0; f < 4; f++) {
            af[f] = *(const bf16x8*)&As[(wm + f * 16 + (lane & 15)) * 32 + (lane >> 4) * 8];
            bf[f] = *(const bf16x8*)&Bs[(wn + f * 16 + (lane & 15)) * 32 + (lane >> 4) * 8];
        }
        #pragma unroll
        for (int fm = 0; fm < 4; fm++)
            #pragma unroll
            for (int fn = 0; fn < 4; fn++)
                acc[fm][fn] = __builtin_amdgcn_mfma_f32_16x16x32_bf16(
                    af[fm], bf[fn], acc[fm][fn], 0, 0, 0);
        __syncthreads();
    }

    // epilogue: col=lane&15, row=(lane>>4)*4+reg
    const int colb = n0 + wn + (lane & 15);
    const int rowb = m0 + wm + (lane >> 4) * 4;
    float bo[4];
    #pragma unroll
    for (int fn = 0; fn < 4; fn++) bo[fn] = b_out[colb + fn * 16];
    #pragma unroll
    for (int fm = 0; fm < 4; fm++) {
        #pragma unroll
        for (int r = 0; r < 4; r++) {
            float* op = out + (size_t)(rowb + fm * 16 + r) * V;
            #pragma unroll
            for (int fn = 0; fn < 4; fn++)
                op[colb + fn * 16] = acc[fm][fn][r] + bo[fn];
        }
    }
}

extern "C" void kernel_launch(void* const* d_in, const int* in_sizes, int n_in,
                              void* d_out, int out_size, void* d_ws, size_t ws_size,
                              hipStream_t stream) {
    const float* h_enc = (const float*)d_in[0];  // (8,200,1,512) = 1600x512
    const float* h_dec = (const float*)d_in[1];  // (8,1,50,512)  = 400x512
    const float* W_enc = (const float*)d_in[2];  // (512,512)
    const float* b_enc = (const float*)d_in[3];  // (512)
    const float* W_dec = (const float*)d_in[4];  // (512,512)
    const float* W_out = (const float*)d_in[5];  // (1024,512)
    const float* b_out = (const float*)d_in[6];  // (1024)
    float* out = (float*)d_out;                  // (8,200,50,1024)

    // workspace layout (~87 MB total)
    float* e = (float*)d_ws;                              // 1600*512 f32
    float* dd = e + 1600 * KD;                            // 400*512 f32
    unsigned short* Wb = (unsigned short*)(dd + 400 * KD); // 1024*512 bf16
    unsigned short* Zb = Wb + (size_t)V * KD;             // 80000*512 bf16

    gemm_ed<<<dim3(25, 8), 256, 0, stream>>>(h_enc, W_enc, b_enc, e, 1600);
    gemm_ed<<<dim3(7, 8), 256, 0, stream>>>(h_dec, W_dec, nullptr, dd, 400);
    cvt_bf16<<<256, 256, 0, stream>>>(W_out, Wb, V * KD);
    tanh_z<<<20000, 256, 0, stream>>>(e, dd, Zb);
    gemm_out_k<<<5000, 256, 0, stream>>>(Zb, Wb, b_out, out);
}

// Round 2
// 474.734 us; speedup vs baseline: 1.1232x; 1.1232x over previous
//
#include <hip/hip_runtime.h>
#include <hip/hip_bf16.h>

// JointNet: out[b,t,u,v] = sum_j tanh(e[b,t,j] + d[b,u,j]) * W_out[v,j] + b_out[v]
//   e = h_enc @ W_enc^T + b_enc   (1600 x 512)
//   d = h_dec @ W_dec^T           (400 x 512)
// Main GEMM: M=80000, N=1024, K=512 (bf16 MFMA, 128x128 tile, BK=64).

typedef short bf16x8 __attribute__((ext_vector_type(8)));
typedef float fx4 __attribute__((ext_vector_type(4)));

static constexpr int KD = 512;   // J = D_enc = D_dec = K
static constexpr int V = 1024;

__device__ inline unsigned short f2bf(float f) {
    union { float f; unsigned u; } v; v.f = f;
    unsigned r = v.u + 0x7fffu + ((v.u >> 16) & 1u);
    return (unsigned short)(r >> 16);
}
__device__ inline float bf2f(unsigned short h) {
    union { float f; unsigned u; } v; v.u = ((unsigned)h) << 16; return v.f;
}
__device__ inline float fast_tanh(float x) {
    float p = __builtin_amdgcn_exp2f(x * 2.885390081777926f);
    return 1.0f - 2.0f * __builtin_amdgcn_rcpf(p + 1.0f);
}
__device__ inline void gld_lds16(const void* g, void* l) {
    __builtin_amdgcn_global_load_lds(
        (const __attribute__((address_space(1))) void*)g,
        (__attribute__((address_space(3))) void*)l, 16, 0, 0);
}

// ---------------- prep: fused e-GEMM / d-GEMM / W_out->bf16 ----------------
// blocks 0..199: e (25 m-tiles x 8 n-tiles); 200..255: d (7 x 8); 256..511: cvt.
// GEMM: 64x64 tile, BK=32, 2-phase bf16 split (hiA*hiW + hiA*loW).
__global__ __launch_bounds__(256) void prep(
    const float* __restrict__ h_enc, const float* __restrict__ W_enc,
    const float* __restrict__ b_enc, const float* __restrict__ h_dec,
    const float* __restrict__ W_dec, const float* __restrict__ W_out,
    float* __restrict__ e, float* __restrict__ dd, unsigned short* __restrict__ Wb) {
    const int bx = blockIdx.x;
    const int t = threadIdx.x;
    if (bx >= 256) {
        // W_out fp32 -> bf16 : 1024*512 = 524288 elems, 256 blocks * 256 thr * 8
        int i = ((bx - 256) * 256 + t) * 8;
        fx4 a = *(const fx4*)(W_out + i);
        fx4 b = *(const fx4*)(W_out + i + 4);
        unsigned short p[8];
        #pragma unroll
        for (int j = 0; j < 4; j++) { p[j] = f2bf(a[j]); p[j + 4] = f2bf(b[j]); }
        *(bf16x8*)(Wb + i) = *(bf16x8*)p;
        return;
    }
    const float* A; const float* W; const float* bias; float* out;
    int Mrows, mb, nb;
    if (bx < 200) { A = h_enc; W = W_enc; bias = b_enc; out = e;  Mrows = 1600; mb = bx >> 3; nb = bx & 7; }
    else { int b2 = bx - 200; A = h_dec; W = W_dec; bias = nullptr; out = dd; Mrows = 400; mb = b2 >> 3; nb = b2 & 7; }

    __shared__ unsigned short As[64 * 32];
    __shared__ unsigned short Ws[64 * 32];
    const int lane = t & 63, wid = t >> 6;
    const int m0 = mb * 64, n0 = nb * 64;
    const int wm = (wid & 1) * 32, wn = (wid >> 1) * 32;

    fx4 acc[2][2];
    const fx4 z4 = {0.f, 0.f, 0.f, 0.f};
    acc[0][0] = z4; acc[0][1] = z4; acc[1][0] = z4; acc[1][1] = z4;

    const int sr = t >> 2;             // staged row 0..63
    const int skc = (t & 3) * 8;       // k chunk start
    const int ar = (m0 + sr < Mrows) ? (m0 + sr) : (Mrows - 1);
    const float* Ap = A + (size_t)ar * KD + skc;
    const float* Wp = W + (size_t)(n0 + sr) * KD + skc;
    unsigned short* asl = &As[sr * 32 + skc];
    unsigned short* wsl = &Ws[sr * 32 + skc];

    for (int ph = 0; ph < 2; ph++) {
        const int wmode = (ph == 1);  // take lo(W) on phase 1
        for (int kb = 0; kb < 16; kb++) {
            const int k0 = kb * 32;
            fx4 a0 = *(const fx4*)(Ap + k0);
            fx4 a1 = *(const fx4*)(Ap + k0 + 4);
            fx4 w0 = *(const fx4*)(Wp + k0);
            fx4 w1 = *(const fx4*)(Wp + k0 + 4);
            unsigned short pa[8], pw[8];
            #pragma unroll
            for (int i = 0; i < 4; i++) {
                unsigned short h;
                pa[i] = f2bf(a0[i]); pa[i + 4] = f2bf(a1[i]);
                h = f2bf(w0[i]); pw[i]     = wmode ? f2bf(w0[i] - bf2f(h)) : h;
                h = f2bf(w1[i]); pw[i + 4] = wmode ? f2bf(w1[i] - bf2f(h)) : h;
            }
            *(bf16x8*)asl = *(bf16x8*)pa;
            *(bf16x8*)wsl = *(bf16x8*)pw;
            __syncthreads();
            bf16x8 af[2], wf[2];
            #pragma unroll
            for (int f = 0; f < 2; f++) {
                af[f] = *(const bf16x8*)&As[(wm + f * 16 + (lane & 15)) * 32 + (lane >> 4) * 8];
                wf[f] = *(const bf16x8*)&Ws[(wn + f * 16 + (lane & 15)) * 32 + (lane >> 4) * 8];
            }
            #pragma unroll
            for (int fm = 0; fm < 2; fm++)
                #pragma unroll
                for (int fn = 0; fn < 2; fn++)
                    acc[fm][fn] = __builtin_amdgcn_mfma_f32_16x16x32_bf16(
                        af[fm], wf[fn], acc[fm][fn], 0, 0, 0);
            __syncthreads();
        }
    }
    // epilogue: C/D layout col=lane&15, row=(lane>>4)*4+reg
    const int colb = n0 + wn + (lane & 15);
    const int rowb = m0 + wm + (lane >> 4) * 4;
    float bo[2];
    bo[0] = bias ? bias[colb] : 0.f;
    bo[1] = bias ? bias[colb + 16] : 0.f;
    #pragma unroll
    for (int fm = 0; fm < 2; fm++) {
        #pragma unroll
        for (int r = 0; r < 4; r++) {
            int row = rowb + fm * 16 + r;
            if (row < Mrows) {
                float* op = out + (size_t)row * KD;
                op[colb] = acc[fm][0][r] + bo[0];
                op[colb + 16] = acc[fm][1][r] + bo[1];
            }
        }
    }
}

// ---------------- Z = tanh(e + d) materialized in bf16 ---------------------
__global__ __launch_bounds__(256) void tanh_z(
    const float* __restrict__ e, const float* __restrict__ d,
    unsigned short* __restrict__ Z) {
    const int t = threadIdx.x;
    const int m = blockIdx.x * 4 + (t >> 6);
    const int kc = (t & 63) * 8;
    const int bt = m / 50;
    const int u = m - bt * 50;
    const int b = m / 10000;
    const float* ep = e + (size_t)bt * KD + kc;
    const float* dp = d + (size_t)(b * 50 + u) * KD + kc;
    fx4 e0 = *(const fx4*)ep, e1 = *(const fx4*)(ep + 4);
    fx4 d0 = *(const fx4*)dp, d1 = *(const fx4*)(dp + 4);
    unsigned short p[8];
    #pragma unroll
    for (int i = 0; i < 4; i++) {
        p[i] = f2bf(fast_tanh(e0[i] + d0[i]));
        p[i + 4] = f2bf(fast_tanh(e1[i] + d1[i]));
    }
    *(bf16x8*)(Z + (size_t)m * KD + kc) = *(bf16x8*)p;
}

// ---------------- main GEMM: out = Z @ W_out^T + b_out ---------------------
// M=80000 (625 tiles), N=1024 (8 tiles), K=512 (8 x BK64).
// 128x128 tile, 256 threads = 4 waves (2x2), wave tile 64x64 (4x4 frags).
// BK=64 as two 128x32 sub-tiles (keeps conflict-free 64B LDS rows and the
// contiguous lane->LDS mapping global_load_lds requires).
__global__ __launch_bounds__(256) void gemm_out_k(
    const unsigned short* __restrict__ Z, const unsigned short* __restrict__ Wb,
    const float* __restrict__ b_out, float* __restrict__ out) {
    __shared__ unsigned short As[2][128 * 32];
    __shared__ unsigned short Bs[2][128 * 32];
    const int t = threadIdx.x;
    const int lane = t & 63, wid = t >> 6;
    const int bid = blockIdx.x;
    const int n0 = (bid & 7) * 128;    // XCD-pinned N tile (bid%8 -> XCD)
    const int m0 = (bid >> 3) * 128;
    const int wm = (wid & 1) * 64, wn = (wid >> 1) * 64;

    fx4 acc[4][4];
    const fx4 z4 = {0.f, 0.f, 0.f, 0.f};
    #pragma unroll
    for (int i = 0; i < 4; i++)
        #pragma unroll
        for (int j = 0; j < 4; j++) acc[i][j] = z4;

    // staging: chunk c = (wid*2+q)*64 + lane covers row c>>2, k-part (c&3)*8
    size_t gA[2], gB[2];
    int lofs[2];
    #pragma unroll
    for (int q = 0; q < 2; q++) {
        int c = (wid * 2 + q) * 64 + lane;
        int r = c >> 2, kc = (c & 3) * 8;
        gA[q] = (size_t)(m0 + r) * KD + kc;
        gB[q] = (size_t)(n0 + r) * KD + kc;
        lofs[q] = (wid * 2 + q) * 512;   // wave-uniform base; HW adds lane*16
    }

    for (int kb = 0; kb < 8; kb++) {
        const int k0 = kb * 64;
        #pragma unroll
        for (int h = 0; h < 2; h++)
            #pragma unroll
            for (int q = 0; q < 2; q++) {
                gld_lds16(Z + gA[q] + k0 + h * 32, &As[h][lofs[q]]);
                gld_lds16(Wb + gB[q] + k0 + h * 32, &Bs[h][lofs[q]]);
            }
        __syncthreads();
        #pragma unroll
        for (int h = 0; h < 2; h++) {
            bf16x8 af[4], bf[4];
            #pragma unroll
            for (int f = 0; f < 4; f++) {
                af[f] = *(const bf16x8*)&As[h][(wm + f * 16 + (lane & 15)) * 32 + (lane >> 4) * 8];
                bf[f] = *(const bf16x8*)&Bs[h][(wn + f * 16 + (lane & 15)) * 32 + (lane >> 4) * 8];
            }
            #pragma unroll
            for (int fm = 0; fm < 4; fm++)
                #pragma unroll
                for (int fn = 0; fn < 4; fn++)
                    acc[fm][fn] = __builtin_amdgcn_mfma_f32_16x16x32_bf16(
                        af[fm], bf[fn], acc[fm][fn], 0, 0, 0);
        }
        __syncthreads();
    }

    // epilogue: col=lane&15, row=(lane>>4)*4+reg
    const int colb = n0 + wn + (lane & 15);
    const int rowb = m0 + wm + (lane >> 4) * 4;
    float bo[4];
    #pragma unroll
    for (int fn = 0; fn < 4; fn++) bo[fn] = b_out[colb + fn * 16];
    #pragma unroll
    for (int fm = 0; fm < 4; fm++) {
        #pragma unroll
        for (int r = 0; r < 4; r++) {
            float* op = out + (size_t)(rowb + fm * 16 + r) * V;
            #pragma unroll
            for (int fn = 0; fn < 4; fn++)
                op[colb + fn * 16] = acc[fm][fn][r] + bo[fn];
        }
    }
}

extern "C" void kernel_launch(void* const* d_in, const int* in_sizes, int n_in,
                              void* d_out, int out_size, void* d_ws, size_t ws_size,
                              hipStream_t stream) {
    const float* h_enc = (const float*)d_in[0];  // (8,200,1,512) = 1600x512
    const float* h_dec = (const float*)d_in[1];  // (8,1,50,512)  = 400x512
    const float* W_enc = (const float*)d_in[2];  // (512,512)
    const float* b_enc = (const float*)d_in[3];  // (512)
    const float* W_dec = (const float*)d_in[4];  // (512,512)
    const float* W_out = (const float*)d_in[5];  // (1024,512)
    const float* b_out = (const float*)d_in[6];  // (1024)
    float* out = (float*)d_out;                  // (8,200,50,1024)

    // workspace layout (~87 MB total)
    float* e = (float*)d_ws;                               // 1600*512 f32
    float* dd = e + 1600 * KD;                             // 400*512 f32
    unsigned short* Wb = (unsigned short*)(dd + 400 * KD); // 1024*512 bf16
    unsigned short* Zb = Wb + (size_t)V * KD;              // 80000*512 bf16

    prep<<<512, 256, 0, stream>>>(h_enc, W_enc, b_enc, h_dec, W_dec, W_out, e, dd, Wb);
    tanh_z<<<20000, 256, 0, stream>>>(e, dd, Zb);
    gemm_out_k<<<5000, 256, 0, stream>>>(Zb, Wb, b_out, out);
}